// Round 1
// baseline (65.801 us; speedup 1.0000x reference)
//
#include <hip/hip_runtime.h>

#define Bsz 32
#define Nn  1024
#define Ff  128

typedef __attribute__((ext_vector_type(8))) short bf16x8;
typedef __attribute__((ext_vector_type(4))) float f32x4;
typedef __attribute__((ext_vector_type(4))) short s16x4;

// round-to-nearest-even f32 -> bf16 (bit pattern as short)
static __device__ inline short f2bf(float f) {
    unsigned u = __builtin_bit_cast(unsigned, f);
    unsigned r = u + 0x7FFFu + ((u >> 16) & 1u);
    return (short)(r >> 16);
}

// ---------------------------------------------------------------------------
// prep: feats f32 -> (a) passthrough copy into d_out tail, (b) bf16 copy in ws
//       w f32 [k][g] -> wT bf16 [g][k]  (k-contiguous for MFMA B fragments)
// ---------------------------------------------------------------------------
__global__ __launch_bounds__(256) void prep_kernel(
    const float* __restrict__ feats,
    const float* __restrict__ w,
    float* __restrict__ out_feats,
    short* __restrict__ feats_bf,
    short* __restrict__ wT_bf)
{
    int gid = blockIdx.x * blockDim.x + threadIdx.x;
    const int total4 = Bsz * Nn * Ff / 4;  // 1,048,576 float4 chunks
    if (gid < total4) {
        float4 v = ((const float4*)feats)[gid];
        ((float4*)out_feats)[gid] = v;
        s16x4 s;
        s.x = f2bf(v.x); s.y = f2bf(v.y); s.z = f2bf(v.z); s.w = f2bf(v.w);
        ((s16x4*)feats_bf)[gid] = s;
    }
    if (gid < Ff * Ff) {
        int g = gid >> 7, k = gid & 127;
        wT_bf[gid] = f2bf(w[k * Ff + g]);
    }
}

// ---------------------------------------------------------------------------
// gemm1: vw[b*N+i][g] = sum_k feats[b*N+i][k] * w[k][g], bf16 out
// block = 64 rows x 128 g, 4 waves (2x2), wave = 32 rows x 64 g
// ---------------------------------------------------------------------------
__global__ __launch_bounds__(256) void gemm1_kernel(
    const float* __restrict__ feats,   // [B*N, F] f32
    const short* __restrict__ wT,      // [F, F] bf16, g-major
    short* __restrict__ vw)            // [B*N, F] bf16
{
    const int row0 = blockIdx.x * 64;
    const int tid  = threadIdx.x;
    const int wid  = tid >> 6;
    const int lane = tid & 63;
    const int wm = wid >> 1, wn = wid & 1;
    const int lr = lane & 15;
    const int kg = lane >> 4;

    const int wrow0 = row0 + wm * 32;
    const int wg0   = wn * 64;

    f32x4 acc[2][4] = {};

    for (int kc = 0; kc < 4; ++kc) {
        int k0 = kc * 32 + kg * 8;
        bf16x8 a[2], b[4];
        for (int mf = 0; mf < 2; ++mf) {
            const float* p = feats + (size_t)(wrow0 + mf * 16 + lr) * Ff + k0;
            float4 v0 = ((const float4*)p)[0];
            float4 v1 = ((const float4*)p)[1];
            a[mf] = (bf16x8){ f2bf(v0.x), f2bf(v0.y), f2bf(v0.z), f2bf(v0.w),
                              f2bf(v1.x), f2bf(v1.y), f2bf(v1.z), f2bf(v1.w) };
        }
        for (int nf = 0; nf < 4; ++nf) {
            const short* p = wT + (size_t)(wg0 + nf * 16 + lr) * Ff + k0;
            b[nf] = *((const bf16x8*)p);
        }
        for (int mf = 0; mf < 2; ++mf)
            for (int nf = 0; nf < 4; ++nf)
                acc[mf][nf] = __builtin_amdgcn_mfma_f32_16x16x32_bf16(
                    a[mf], b[nf], acc[mf][nf], 0, 0, 0);
    }

    // C/D layout: col = lane&15, row = (lane>>4)*4 + reg
    for (int mf = 0; mf < 2; ++mf) {
        int row = wrow0 + mf * 16 + kg * 4;
        for (int nf = 0; nf < 4; ++nf) {
            int g = wg0 + nf * 16 + lr;
            for (int r = 0; r < 4; ++r)
                vw[(size_t)(row + r) * Ff + g] = f2bf(acc[mf][nf][r]);
        }
    }
}

// ---------------------------------------------------------------------------
// gemm2: y[b][i][j] = sum_g vw[b][i][g] * feats[b][j][g] + bias
// grid = 32 batches x 8 mt x 8 nt; block 256 thr = 4 waves (2x2),
// wave = 64x64 output, 4x4 fragments of 16x16, K=128 in 4 chunks of 32
// ---------------------------------------------------------------------------
__global__ __launch_bounds__(256) void gemm2_kernel(
    const short* __restrict__ vw,     // [B, N, F] bf16
    const short* __restrict__ fb,     // [B, N, F] bf16
    const float* __restrict__ bias,
    float* __restrict__ y)            // [B, N, N]
{
    int blk  = blockIdx.x;
    int bidx = blk >> 6;
    int t    = blk & 63;
    int mt = t >> 3, nt = t & 7;
    int tid = threadIdx.x;
    int wid = tid >> 6, lane = tid & 63;
    int wm = wid >> 1, wn = wid & 1;
    int lr = lane & 15, kg = lane >> 4;

    const short* A  = vw + (size_t)bidx * Nn * Ff;
    const short* Bp = fb + (size_t)bidx * Nn * Ff;
    int am0 = mt * 128 + wm * 64;
    int bn0 = nt * 128 + wn * 64;

    f32x4 acc[4][4] = {};

    for (int kc = 0; kc < 4; ++kc) {
        int k0 = kc * 32 + kg * 8;
        bf16x8 a[4], b[4];
        for (int mf = 0; mf < 4; ++mf)
            a[mf] = *((const bf16x8*)(A + (size_t)(am0 + mf * 16 + lr) * Ff + k0));
        for (int nf = 0; nf < 4; ++nf)
            b[nf] = *((const bf16x8*)(Bp + (size_t)(bn0 + nf * 16 + lr) * Ff + k0));
        for (int mf = 0; mf < 4; ++mf)
            for (int nf = 0; nf < 4; ++nf)
                acc[mf][nf] = __builtin_amdgcn_mfma_f32_16x16x32_bf16(
                    a[mf], b[nf], acc[mf][nf], 0, 0, 0);
    }

    float bv = bias[0];
    float* Y = y + (size_t)bidx * Nn * Nn;
    for (int mf = 0; mf < 4; ++mf) {
        int row = am0 + mf * 16 + kg * 4;
        for (int nf = 0; nf < 4; ++nf) {
            int col = bn0 + nf * 16 + lr;
            float* p = Y + (size_t)row * Nn + col;
            for (int r = 0; r < 4; ++r)
                p[(size_t)r * Nn] = acc[mf][nf][r] + bv;
        }
    }
}

extern "C" void kernel_launch(void* const* d_in, const int* in_sizes, int n_in,
                              void* d_out, int out_size, void* d_ws, size_t ws_size,
                              hipStream_t stream) {
    const float* feats = (const float*)d_in[1];
    const float* w     = (const float*)d_in[2];
    const float* bias  = (const float*)d_in[3];
    float* y = (float*)d_out;
    float* out_feats = y + (size_t)Bsz * Nn * Nn;

    short* vw = (short*)d_ws;
    short* fb = vw + (size_t)Bsz * Nn * Ff;
    short* wT = fb + (size_t)Bsz * Nn * Ff;

    prep_kernel<<<4096, 256, 0, stream>>>(feats, w, out_feats, fb, wT);
    gemm1_kernel<<<512, 256, 0, stream>>>(feats, wT, vw);
    gemm2_kernel<<<32 * 64, 256, 0, stream>>>(vw, fb, bias, y);
}